// Round 1
// baseline (476.705 us; speedup 1.0000x reference)
//
#include <hip/hip_runtime.h>
#include <hip/hip_bf16.h>
#include <stdint.h>

#define B_   64
#define T_   2048
#define ENC_ 1024
#define DEC_ 1024
#define A_   512
#define M_   (B_ * T_)   // 131072

#define BM 128
#define BN 256
#define BK 64

typedef __bf16 bf16x8 __attribute__((ext_vector_type(8)));
typedef float  f32x4  __attribute__((ext_vector_type(4)));
typedef unsigned short u16;

__device__ __forceinline__ u16 f2bf(float x) {
    uint32_t u = __float_as_uint(x);
    u += 0x7FFFu + ((u >> 16) & 1u);   // round-to-nearest-even
    return (u16)(u >> 16);
}

__device__ __forceinline__ float fast_tanh(float x) {
    float ax = fabsf(x);
    float e  = __expf(-2.0f * ax);     // in (0,1]
    float t  = (1.0f - e) / (1.0f + e);
    return copysignf(t, x);
}

// ---------------- U transpose + convert: Ut[n][k] = bf16(U[k][n]) ----------
__global__ __launch_bounds__(256) void k_transpose_U(
        const float* __restrict__ U, u16* __restrict__ Ut) {
    int idx = blockIdx.x * 256 + threadIdx.x;     // over 1024*512
    if (idx >= ENC_ * A_) return;
    int k = idx / A_, n = idx % A_;
    Ut[n * ENC_ + k] = f2bf(U[idx]);
}

// ---------------- f2[b][a] = sum_e s[b][e] * W[e][a]  (fp32) ---------------
__global__ __launch_bounds__(256) void k_f2(
        const float* __restrict__ s, const float* __restrict__ W,
        float* __restrict__ f2) {
    int b = blockIdx.x;
    int a0 = threadIdx.x;              // 256 threads, 2 columns each
    const float* srow = s + (size_t)b * DEC_;
    float acc0 = 0.f, acc1 = 0.f;
    for (int e = 0; e < DEC_; ++e) {
        float sv = srow[e];
        acc0 = fmaf(sv, W[(size_t)e * A_ + a0],       acc0);
        acc1 = fmaf(sv, W[(size_t)e * A_ + a0 + 256], acc1);
    }
    f2[(size_t)b * A_ + a0]       = acc0;
    f2[(size_t)b * A_ + a0 + 256] = acc1;
}

// ---------------- fused GEMM + tanh + dot(V): partial e --------------------
// grid (M/BM, A/BN) = (1024, 2), 512 threads (8 waves, 2x4), wave tile 64x64
__global__ __launch_bounds__(512) void k_gemm_e(
        const float* __restrict__ h, const u16* __restrict__ Ut,
        const float* __restrict__ f2, const float* __restrict__ V,
        float* __restrict__ e_part) {
    __shared__ u16 Alds[BM * BK];      // [128][64]  row-major
    __shared__ u16 Blds[BN * BK];      // [256][64]  n-major (U^T tile)

    const int tid  = threadIdx.x;
    const int lane = tid & 63;
    const int wid  = tid >> 6;         // 0..7
    const int wr   = wid >> 2;         // 0..1
    const int wc   = wid & 3;          // 0..3
    const int lr   = lane & 15;
    const int g    = lane >> 4;

    const int brow = blockIdx.x * BM;
    const int bcol = blockIdx.y * BN;
    const int b    = brow / T_;        // T_ divisible by BM -> uniform per block

    f32x4 acc[4][4] = {};

    for (int kt = 0; kt < ENC_ / BK; ++kt) {
        const int k0 = kt * BK;

        // ---- stage B (bf16, direct global->LDS, 4 issues of 8KB) ----
#pragma unroll
        for (int it = 0; it < 4; ++it) {
            int flat = (it * 512 + tid) * 8;              // element in Blds
            int n = flat >> 6, kc = flat & 63;
            const u16* src = Ut + (size_t)(bcol + n) * ENC_ + k0 + kc;
            u16* dst = &Blds[(size_t)(it * 512 + wid * 64) * 8]; // wave-uniform
            __builtin_amdgcn_global_load_lds(
                (const __attribute__((address_space(1))) void*)src,
                (__attribute__((address_space(3))) void*)dst, 16, 0, 0);
        }

        // ---- stage A (fp32 -> bf16 via regs) ----
#pragma unroll
        for (int it = 0; it < 4; ++it) {
            int flat = (it * 512 + tid) * 4;              // element in Alds
            int r = flat >> 6, c = flat & 63;
            float4 v = *(const float4*)(h + (size_t)(brow + r) * ENC_ + k0 + c);
            ushort4 w;
            w.x = f2bf(v.x); w.y = f2bf(v.y); w.z = f2bf(v.z); w.w = f2bf(v.w);
            *(ushort4*)&Alds[flat] = w;
        }
        __syncthreads();   // compiler drains vmcnt+lgkmcnt here

#pragma unroll
        for (int kk = 0; kk < 2; ++kk) {
            bf16x8 af[4], bfr[4];
#pragma unroll
            for (int mf = 0; mf < 4; ++mf)
                af[mf] = *(const bf16x8*)&Alds[(wr * 64 + mf * 16 + lr) * 64 + kk * 32 + g * 8];
#pragma unroll
            for (int nf = 0; nf < 4; ++nf)
                bfr[nf] = *(const bf16x8*)&Blds[(wc * 64 + nf * 16 + lr) * 64 + kk * 32 + g * 8];
#pragma unroll
            for (int mf = 0; mf < 4; ++mf)
#pragma unroll
                for (int nf = 0; nf < 4; ++nf)
                    acc[mf][nf] = __builtin_amdgcn_mfma_f32_16x16x32_bf16(
                        af[mf], bfr[nf], acc[mf][nf], 0, 0, 0);
        }
        __syncthreads();
    }

    // ---- epilogue: e_partial[m] = sum_n tanh(acc + f2) * V ----
    float vv[4], ff[4];
#pragma unroll
    for (int nf = 0; nf < 4; ++nf) {
        int n = bcol + wc * 64 + nf * 16 + lr;
        vv[nf] = V[n];
        ff[nf] = f2[(size_t)b * A_ + n];
    }
    const int p = blockIdx.y * 4 + wc;                    // 8 partial slices
    float* ep = e_part + (size_t)p * M_ + brow + wr * 64;
#pragma unroll
    for (int mf = 0; mf < 4; ++mf) {
        float sums[4];
#pragma unroll
        for (int i = 0; i < 4; ++i) {
            float sv = 0.f;
#pragma unroll
            for (int nf = 0; nf < 4; ++nf) {
                float x = acc[mf][nf][i] + ff[nf];
                sv = fmaf(fast_tanh(x), vv[nf], sv);
            }
#pragma unroll
            for (int m = 1; m < 16; m <<= 1)
                sv += __shfl_xor(sv, m, 64);              // reduce 16 cols
            sums[i] = sv;
        }
        if (lr == 0) {
#pragma unroll
            for (int i = 0; i < 4; ++i)
                ep[mf * 16 + g * 4 + i] = sums[i];
        }
    }
}

// ---------------- softmax over T per batch --------------------------------
__global__ __launch_bounds__(256) void k_softmax(
        const float* __restrict__ e_part, float* __restrict__ a_out) {
    const int b = blockIdx.x, tid = threadIdx.x;
    const int lane = tid & 63, w = tid >> 6;
    __shared__ float red[4], red2[4];

    float ls[8];
    float lmax = -1e30f;
#pragma unroll
    for (int i = 0; i < 8; ++i) {
        size_t m = (size_t)b * T_ + i * 256 + tid;
        float sv = 0.f;
#pragma unroll
        for (int p = 0; p < 8; ++p) sv += e_part[(size_t)p * M_ + m];
        ls[i] = sv;
        lmax = fmaxf(lmax, sv);
    }
#pragma unroll
    for (int m = 1; m < 64; m <<= 1) lmax = fmaxf(lmax, __shfl_xor(lmax, m, 64));
    if (lane == 0) red[w] = lmax;
    __syncthreads();
    float bmax = fmaxf(fmaxf(red[0], red[1]), fmaxf(red[2], red[3]));

    float lsum = 0.f;
#pragma unroll
    for (int i = 0; i < 8; ++i) { ls[i] = __expf(ls[i] - bmax); lsum += ls[i]; }
#pragma unroll
    for (int m = 1; m < 64; m <<= 1) lsum += __shfl_xor(lsum, m, 64);
    if (lane == 0) red2[w] = lsum;
    __syncthreads();
    float inv = 1.0f / (red2[0] + red2[1] + red2[2] + red2[3]);

#pragma unroll
    for (int i = 0; i < 8; ++i)
        a_out[(size_t)b * T_ + i * 256 + tid] = ls[i] * inv;
}

// ---------------- context partials: c_part[tc][b][e] ----------------------
__global__ __launch_bounds__(256) void k_ctx_part(
        const float* __restrict__ h, const float* __restrict__ a,
        float* __restrict__ c_part) {
    const int b = blockIdx.x, tc = blockIdx.y, tid = threadIdx.x;
    __shared__ float alds[512];
    for (int i = tid; i < 512; i += 256)
        alds[i] = a[(size_t)b * T_ + tc * 512 + i];
    __syncthreads();

    float4 acc = {0.f, 0.f, 0.f, 0.f};
    const float* hb = h + ((size_t)b * T_ + (size_t)tc * 512) * ENC_ + tid * 4;
    for (int t = 0; t < 512; ++t) {
        float av = alds[t];
        float4 hv = *(const float4*)(hb + (size_t)t * ENC_);
        acc.x = fmaf(av, hv.x, acc.x);
        acc.y = fmaf(av, hv.y, acc.y);
        acc.z = fmaf(av, hv.z, acc.z);
        acc.w = fmaf(av, hv.w, acc.w);
    }
    *(float4*)&c_part[((size_t)(tc * 64 + b)) * ENC_ + tid * 4] = acc;
}

// ---------------- final context reduce ------------------------------------
__global__ __launch_bounds__(256) void k_ctx_final(
        const float* __restrict__ c_part, float* __restrict__ c_out) {
    int idx = blockIdx.x * 256 + threadIdx.x;   // 16384 threads
    int off = idx * 4;
    float4 sv = {0.f, 0.f, 0.f, 0.f};
#pragma unroll
    for (int tc = 0; tc < 4; ++tc) {
        float4 v = *(const float4*)&c_part[(size_t)tc * 64 * 1024 + off];
        sv.x += v.x; sv.y += v.y; sv.z += v.z; sv.w += v.w;
    }
    *(float4*)&c_out[off] = sv;
}

extern "C" void kernel_launch(void* const* d_in, const int* in_sizes, int n_in,
                              void* d_out, int out_size, void* d_ws, size_t ws_size,
                              hipStream_t stream) {
    const float* h = (const float*)d_in[0];
    const float* s = (const float*)d_in[1];
    const float* U = (const float*)d_in[2];
    const float* W = (const float*)d_in[3];
    const float* V = (const float*)d_in[4];

    float* out   = (float*)d_out;
    float* c_out = out;                         // [64][1][1024] -> 65536 floats
    float* a_out = out + 64 * 1024;             // [64][2048][1] -> 131072 floats

    char* ws = (char*)d_ws;
    u16*   Ut     = (u16*)ws;                                       // 1 MB
    float* f2     = (float*)(ws + (1 << 20));                       // 128 KB
    float* e_part = (float*)(ws + (1 << 20) + (128 << 10));         // 4 MB
    float* c_part = (float*)(ws + (1 << 20) + (128 << 10) + (4 << 20)); // 1 MB

    k_transpose_U<<<2048, 256, 0, stream>>>(U, Ut);
    k_f2<<<64, 256, 0, stream>>>(s, W, f2);

    dim3 gg(M_ / BM, A_ / BN);                  // (1024, 2)
    k_gemm_e<<<gg, 512, 0, stream>>>(h, Ut, f2, V, e_part);

    k_softmax<<<64, 256, 0, stream>>>(e_part, a_out);

    dim3 gc(64, 4);
    k_ctx_part<<<gc, 256, 0, stream>>>(h, a_out, c_part);
    k_ctx_final<<<64, 256, 0, stream>>>(c_part, c_out);
}